// Round 17
// baseline (42.342 us; speedup 1.0000x reference)
//
#include <hip/hip_runtime.h>

// L=32768, N=32, E=H=1, BS=256 -> 4096 rank-1 softmax problems:
//   out_i = sum_j 2^(a'_i k_j) v_j / sum_j 2^(a'_i k_j),  a' = (wq q + bq) log2e.
// No max-subtraction (f32-safe, scale-invariant; validated R5-R16).
//
// R17 = R16 (segmented-Taylor moments, 33.6us) + occupancy & exp cuts:
//  - one problem per WG of 128 threads (2 waves): 8192 waves = 8/SIMD
//    (R16 had 4/SIMD and was latency-bound: 80k cy wall vs ~20k busy).
//  - E-recurrence: 2^(a c_s) = E * G^s, G = 2^(a segw): 4 exps/thread total
//    (R16: 128). One v_pk_mul per segment replaces 4 exps.
//  - deg-6 Horner (14 floats/seg -> 4 uniform ds_read_b128), tail < 6e-5 rel.
//  - sort runs on wave 0 only -> lane-ordered LDS atomics, deterministic.

#define LL    32768
#define NN    32
#define BSZ   256
#define NBLK  (LL / BSZ)
#define NSEG  32
#define LOG2E 1.4426950408889634f
#define LN2   0.6931471805599453f

typedef float v2f __attribute__((ext_vector_type(2)));

__global__ __launch_bounds__(128, 8) void BlockCrossAttn_kernel(
    const float* __restrict__ q_in, const float* __restrict__ k_in,
    const float* __restrict__ v_in,
    const float* __restrict__ ipw,  const float* __restrict__ ipb,
    const float* __restrict__ opw,  const float* __restrict__ opb,
    float* __restrict__ out)
{
    const int t    = threadIdx.x;        // 0..127
    const int lane = t & 63;
    const int w    = t >> 6;             // wave 0/1
    const int prob = blockIdx.x;         // one problem per WG
    const int blk  = prob >> 5;
    const int n    = prob & 31;

    const float wq = ipw[0], wk = ipw[1], wv = ipw[2];
    const float bq = ipb[0], bk = ipb[1], bv = ipb[2];

    __shared__ alignas(16) float2 raw[BSZ];          // unsorted (k,v) by row
    __shared__ alignas(16) float2 skv[BSZ];          // sorted (k,v)
    __shared__ alignas(16) float  momH[2][NSEG][16]; // per-half moments
    __shared__ int   hist[128];
    __shared__ float red[4];

    // ---- gather rows t and t+128; project ----
    const int gi0 = (blk * BSZ + t) * NN + n;
    const int gi1 = gi0 + 128 * NN;
    const float a0 = fmaf(q_in[gi0], wq, bq) * LOG2E;
    const float a1 = fmaf(q_in[gi1], wq, bq) * LOG2E;
    const float k0 = fmaf(k_in[gi0], wk, bk);
    const float k1 = fmaf(k_in[gi1], wk, bk);
    const float v0 = fmaf(v_in[gi0], wv, bv);
    const float v1 = fmaf(v_in[gi1], wv, bv);
    raw[t]       = make_float2(k0, v0);
    raw[t + 128] = make_float2(k1, v1);
    hist[t] = 0;

    // block kmin/kmax
    float mn = fminf(k0, k1), mx = fmaxf(k0, k1);
    #pragma unroll
    for (int off = 32; off >= 1; off >>= 1) {
        mn = fminf(mn, __shfl_xor(mn, off));
        mx = fmaxf(mx, __shfl_xor(mx, off));
    }
    if (lane == 0) { red[w] = mn; red[2 + w] = mx; }
    __syncthreads();                                   // raw, hist, red visible
    const float kmn  = fminf(red[0], red[1]);
    const float kmx  = fmaxf(red[2], red[3]);
    const float rng  = kmx - kmn;
    const float binv = (rng > 0.f) ? (127.99f / rng) : 0.f;
    const float segw = rng * (1.0f / NSEG);

    // ---- counting sort by 7-bit quantized k: wave 0 only (deterministic) ----
    if (w == 0) {
        #pragma unroll
        for (int r = 0; r < 4; ++r) {
            const float kk = raw[r * 64 + lane].x;
            int b = (int)((kk - kmn) * binv);
            b = (b < 0) ? 0 : ((b > 127) ? 127 : b);
            atomicAdd(&hist[b], 1);
        }
    }
    __syncthreads();
    if (w == 0) {
        const int c0 = hist[lane];
        const int c1 = hist[lane + 64];
        int i0 = c0, i1 = c1;
        #pragma unroll
        for (int off = 1; off <= 32; off <<= 1) {
            const int t0 = __shfl_up(i0, off);
            const int t1 = __shfl_up(i1, off);
            if (lane >= off) { i0 += t0; i1 += t1; }
        }
        const int tot0 = __shfl(i0, 63);
        hist[lane]      = i0 - c0;          // exclusive starts
        hist[lane + 64] = i1 - c1 + tot0;
    }
    __syncthreads();
    if (w == 0) {
        #pragma unroll
        for (int r = 0; r < 4; ++r) {
            const float2 kv = raw[r * 64 + lane];
            int b = (int)((kv.x - kmn) * binv);
            b = (b < 0) ? 0 : ((b > 127) ? 127 : b);
            const int slot = atomicAdd(&hist[b], 1);   // lane-ordered
            skv[slot] = kv;
        }
    }
    __syncthreads();
    // hist[b] now = END offset of bin b

    // ---- moments: 64 tasks (seg x part) x 2 halves over 128 threads ----
    {
        const int s    = t & 31;
        const int prt  = (t >> 5) & 1;    // 0: den (w=1), 1: num (w=v)
        const int half = t >> 6;
        const int beg  = (s == 0) ? 0 : hist[4 * s - 1];
        const int end  = hist[4 * s + 3];
        const float cs = kmn + (s + 0.5f) * segw;
        float m0=0.f,m1=0.f,m2=0.f,m3=0.f,m4=0.f,m5=0.f,m6=0.f;
        for (int e = beg + half; e < end; e += 2) {
            const float2 kv = skv[e];
            const float dk = kv.x - cs;
            float p = prt ? kv.y : 1.0f;
            m0 += p; p *= dk;
            m1 += p; p *= dk;
            m2 += p; p *= dk;
            m3 += p; p *= dk;
            m4 += p; p *= dk;
            m5 += p; p *= dk;
            m6 += p;
        }
        float* mp = &momH[half][s][prt * 8];
        mp[0] = m0;
        mp[1] = m1;
        mp[2] = m2 * 0.5f;
        mp[3] = m3 * (1.f / 6.f);
        mp[4] = m4 * (1.f / 24.f);
        mp[5] = m5 * (1.f / 120.f);
        mp[6] = m6 * (1.f / 720.f);
        mp[7] = 0.f;
    }
    __syncthreads();

    // ---- combine halves: 512 floats = 128 float4, one per thread ----
    {
        float4* h0 = (float4*)&momH[0][0][0];
        const float4* h1 = (const float4*)&momH[1][0][0];
        float4 x = h0[t];
        const float4 y = h1[t];
        x.x += y.x; x.y += y.y; x.z += y.z; x.w += y.w;
        h0[t] = x;
    }
    __syncthreads();

    // ---- row loop: 2 rows/thread, 32 segments, E-recurrence ----
    const v2f u = {a0 * LN2, a1 * LN2};
    const float c0s = kmn + 0.5f * segw;
    v2f E, G;
    E.x = __builtin_amdgcn_exp2f(a0 * c0s);
    E.y = __builtin_amdgcn_exp2f(a1 * c0s);
    G.x = __builtin_amdgcn_exp2f(a0 * segw);
    G.y = __builtin_amdgcn_exp2f(a1 * segw);

    v2f den = {0.f, 0.f}, num = {0.f, 0.f};
    const float4* __restrict__ M4 = (const float4*)&momH[0][0][0];

    #pragma unroll 4
    for (int s = 0; s < NSEG; ++s) {
        const float4 D0 = M4[s * 4 + 0];   // den d0..3   (uniform b128)
        const float4 D1 = M4[s * 4 + 1];   // den d4..6
        const float4 N0 = M4[s * 4 + 2];   // num d0..3
        const float4 N1 = M4[s * 4 + 3];   // num d4..6

        v2f hd = {D1.z, D1.z};
        hd = __builtin_elementwise_fma(hd, u, (v2f){D1.y, D1.y});
        hd = __builtin_elementwise_fma(hd, u, (v2f){D1.x, D1.x});
        hd = __builtin_elementwise_fma(hd, u, (v2f){D0.w, D0.w});
        hd = __builtin_elementwise_fma(hd, u, (v2f){D0.z, D0.z});
        hd = __builtin_elementwise_fma(hd, u, (v2f){D0.y, D0.y});
        hd = __builtin_elementwise_fma(hd, u, (v2f){D0.x, D0.x});

        v2f hn = {N1.z, N1.z};
        hn = __builtin_elementwise_fma(hn, u, (v2f){N1.y, N1.y});
        hn = __builtin_elementwise_fma(hn, u, (v2f){N1.x, N1.x});
        hn = __builtin_elementwise_fma(hn, u, (v2f){N0.w, N0.w});
        hn = __builtin_elementwise_fma(hn, u, (v2f){N0.z, N0.z});
        hn = __builtin_elementwise_fma(hn, u, (v2f){N0.y, N0.y});
        hn = __builtin_elementwise_fma(hn, u, (v2f){N0.x, N0.x});

        den = __builtin_elementwise_fma(E, hd, den);
        num = __builtin_elementwise_fma(E, hn, num);
        E = E * G;                          // v_pk_mul: next segment's 2^(a c_s)
    }

    const float wo = opw[0], bo = opb[0];
    out[gi0] = fmaf(num.x / den.x, wo, bo);
    out[gi1] = fmaf(num.y / den.y, wo, bo);
}

extern "C" void kernel_launch(void* const* d_in, const int* in_sizes, int n_in,
                              void* d_out, int out_size, void* d_ws, size_t ws_size,
                              hipStream_t stream) {
    const float* q   = (const float*)d_in[0];
    const float* k   = (const float*)d_in[1];
    const float* v   = (const float*)d_in[2];
    const float* ipw = (const float*)d_in[3];
    const float* ipb = (const float*)d_in[4];
    const float* opw = (const float*)d_in[5];
    const float* opb = (const float*)d_in[6];
    float* out = (float*)d_out;

    dim3 grid(NBLK * NN);   // 4096 WGs: one problem each, 2 waves
    dim3 block(128);
    BlockCrossAttn_kernel<<<grid, block, 0, stream>>>(q, k, v, ipw, ipb, opw, opb, out);
}

// Round 18
// 33.789 us; speedup vs baseline: 1.2531x; 1.2531x over previous
//
#include <hip/hip_runtime.h>

// L=32768, N=32, E=H=1, BS=256 -> 4096 rank-1 softmax problems:
//   out_i = sum_j 2^(a'_i k_j) v_j / sum_j 2^(a'_i k_j),  a' = (wq q + bq) log2e.
// No max-subtraction (f32-safe, scale-invariant; validated R5-R17).
//
// R18 = R16's segmented-Taylor moments (33.6us) restructured as ONE PROBLEM
// PER 64-THREAD WG (4096 WGs): barriers are single-wave (no cross-problem
// coupling -- R17 showed coupling+conflicts cost more than occupancy gains).
//  - counting sort by 7-bit quantized k (verified R13/R16), wave-private LDS.
//  - moments: 2 lanes/segment over CONTIGUOUS half-ranges (R17's stride-2
//    interleave caused 976k bank conflicts), combined via shfl_xor(1).
//  - row loop: deg-6 Horner (4 uniform ds_read_b128/seg) + E-recurrence with
//    two independent chains (even/odd segs): 8 exps/thread total (R16: 128).

#define LL    32768
#define NN    32
#define BSZ   256
#define NBLK  (LL / BSZ)
#define NSEG  32
#define LOG2E 1.4426950408889634f
#define LN2   0.6931471805599453f

typedef float v2f __attribute__((ext_vector_type(2)));

__device__ __forceinline__ v2f horner6(v2f u, float4 f0, float4 f1) {
    // coefficients f0 = {c0,c1,c2,c3}, f1 = {c4,c5,c6,pad}
    v2f h = {f1.z, f1.z};
    h = __builtin_elementwise_fma(h, u, (v2f){f1.y, f1.y});
    h = __builtin_elementwise_fma(h, u, (v2f){f1.x, f1.x});
    h = __builtin_elementwise_fma(h, u, (v2f){f0.w, f0.w});
    h = __builtin_elementwise_fma(h, u, (v2f){f0.z, f0.z});
    h = __builtin_elementwise_fma(h, u, (v2f){f0.y, f0.y});
    h = __builtin_elementwise_fma(h, u, (v2f){f0.x, f0.x});
    return h;
}

__global__ __launch_bounds__(64) void BlockCrossAttn_kernel(
    const float* __restrict__ q_in, const float* __restrict__ k_in,
    const float* __restrict__ v_in,
    const float* __restrict__ ipw,  const float* __restrict__ ipb,
    const float* __restrict__ opw,  const float* __restrict__ opb,
    float* __restrict__ out)
{
    const int lane = threadIdx.x;        // 0..63, one wave per WG
    const int prob = blockIdx.x;         // 0..4095
    const int blk  = prob >> 5;
    const int n    = prob & 31;

    const float wq = ipw[0], wk = ipw[1], wv = ipw[2];
    const float bq = ipb[0], bk = ipb[1], bv = ipb[2];

    __shared__ alignas(16) float2 skv[BSZ];       // sorted (k, v)
    __shared__ alignas(16) float  mom[NSEG][16];  // D0..D6,_,N0..N6,_  (/d!)
    __shared__ int hist[128];

    // ---- gather + project: lane owns rows lane+{0,64,128,192} ----
    float a[4], kr[4], vr[4];
    #pragma unroll
    for (int r = 0; r < 4; ++r) {
        const int gi = (blk * BSZ + r * 64 + lane) * NN + n;
        a[r]  = fmaf(q_in[gi], wq, bq) * LOG2E;
        kr[r] = fmaf(k_in[gi], wk, bk);
        vr[r] = fmaf(v_in[gi], wv, bv);
    }

    // wave kmin/kmax
    float kmn = fminf(fminf(kr[0], kr[1]), fminf(kr[2], kr[3]));
    float kmx = fmaxf(fmaxf(kr[0], kr[1]), fmaxf(kr[2], kr[3]));
    #pragma unroll
    for (int off = 32; off >= 1; off >>= 1) {
        kmn = fminf(kmn, __shfl_xor(kmn, off));
        kmx = fmaxf(kmx, __shfl_xor(kmx, off));
    }
    const float rng  = kmx - kmn;
    const float binv = (rng > 0.f) ? (127.99f / rng) : 0.f;
    const float segw = rng * (1.0f / NSEG);

    // ---- counting sort by 7-bit quantized k (verified R13/R16) ----
    hist[lane]      = 0;
    hist[lane + 64] = 0;
    __syncthreads();                      // single-wave barrier: cheap

    int bin[4];
    #pragma unroll
    for (int r = 0; r < 4; ++r) {
        int b = (int)((kr[r] - kmn) * binv);
        bin[r] = (b < 0) ? 0 : ((b > 127) ? 127 : b);
        atomicAdd(&hist[bin[r]], 1);      // wave-private, lane-ordered
    }
    __syncthreads();

    {
        const int c0 = hist[lane];
        const int c1 = hist[lane + 64];
        int i0 = c0, i1 = c1;
        #pragma unroll
        for (int off = 1; off <= 32; off <<= 1) {
            const int t0 = __shfl_up(i0, off);
            const int t1 = __shfl_up(i1, off);
            if (lane >= off) { i0 += t0; i1 += t1; }
        }
        const int tot0 = __shfl(i0, 63);
        hist[lane]      = i0 - c0;        // exclusive starts
        hist[lane + 64] = i1 - c1 + tot0;
    }
    __syncthreads();

    #pragma unroll
    for (int r = 0; r < 4; ++r) {
        const int slot = atomicAdd(&hist[bin[r]], 1);
        skv[slot] = make_float2(kr[r], vr[r]);
    }
    __syncthreads();
    // hist[b] = END offset of bin b

    // ---- moments: 2 lanes per segment, CONTIGUOUS half-ranges ----
    {
        const int s    = lane >> 1;
        const int half = lane & 1;
        const int beg0 = (s == 0) ? 0 : hist[4 * s - 1];
        const int end0 = hist[4 * s + 3];
        const int mid  = beg0 + ((end0 - beg0 + 1) >> 1);
        const int beg  = half ? mid  : beg0;
        const int end  = half ? end0 : mid;
        const float cs = kmn + (s + 0.5f) * segw;

        float m0=0.f,m1=0.f,m2=0.f,m3=0.f,m4=0.f,m5=0.f,m6=0.f;
        float n0=0.f,n1=0.f,n2=0.f,n3=0.f,n4=0.f,n5=0.f,n6=0.f;
        for (int e = beg; e < end; ++e) {
            const float2 kv = skv[e];
            const float dk = kv.x - cs;
            const float vv = kv.y;
            const float p1 = dk, p2 = p1 * dk, p3 = p2 * dk;
            const float p4 = p3 * dk, p5 = p4 * dk, p6 = p5 * dk;
            m0 += 1.f; m1 += p1; m2 += p2; m3 += p3; m4 += p4; m5 += p5; m6 += p6;
            n0 += vv;
            n1 = fmaf(vv, p1, n1); n2 = fmaf(vv, p2, n2); n3 = fmaf(vv, p3, n3);
            n4 = fmaf(vv, p4, n4); n5 = fmaf(vv, p5, n5); n6 = fmaf(vv, p6, n6);
        }
        // combine the two halves (partner = lane^1)
        m0 += __shfl_xor(m0, 1); m1 += __shfl_xor(m1, 1); m2 += __shfl_xor(m2, 1);
        m3 += __shfl_xor(m3, 1); m4 += __shfl_xor(m4, 1); m5 += __shfl_xor(m5, 1);
        m6 += __shfl_xor(m6, 1);
        n0 += __shfl_xor(n0, 1); n1 += __shfl_xor(n1, 1); n2 += __shfl_xor(n2, 1);
        n3 += __shfl_xor(n3, 1); n4 += __shfl_xor(n4, 1); n5 += __shfl_xor(n5, 1);
        n6 += __shfl_xor(n6, 1);

        float4* mp = (float4*)&mom[s][0];
        if (!half) {
            mp[0] = make_float4(m0, m1, m2 * 0.5f, m3 * (1.f / 6.f));
            mp[1] = make_float4(m4 * (1.f / 24.f), m5 * (1.f / 120.f),
                                m6 * (1.f / 720.f), 0.f);
        } else {
            mp[2] = make_float4(n0, n1, n2 * 0.5f, n3 * (1.f / 6.f));
            mp[3] = make_float4(n4 * (1.f / 24.f), n5 * (1.f / 120.f),
                                n6 * (1.f / 720.f), 0.f);
        }
    }
    __syncthreads();

    // ---- row loop: 4 rows/thread, E-recurrence (2 chains), deg-6 Horner ----
    const v2f u01 = {a[0] * LN2, a[1] * LN2};
    const v2f u23 = {a[2] * LN2, a[3] * LN2};
    const float c0s = kmn + 0.5f * segw;

    v2f Ee01, Ee23, g01, g23;
    Ee01.x = __builtin_amdgcn_exp2f(a[0] * c0s);
    Ee01.y = __builtin_amdgcn_exp2f(a[1] * c0s);
    Ee23.x = __builtin_amdgcn_exp2f(a[2] * c0s);
    Ee23.y = __builtin_amdgcn_exp2f(a[3] * c0s);
    g01.x  = __builtin_amdgcn_exp2f(a[0] * segw);
    g01.y  = __builtin_amdgcn_exp2f(a[1] * segw);
    g23.x  = __builtin_amdgcn_exp2f(a[2] * segw);
    g23.y  = __builtin_amdgcn_exp2f(a[3] * segw);
    const v2f G2_01 = g01 * g01;
    const v2f G2_23 = g23 * g23;
    v2f Eo01 = Ee01 * g01;
    v2f Eo23 = Ee23 * g23;

    v2f de01 = {0.f,0.f}, do01 = {0.f,0.f}, de23 = {0.f,0.f}, do23 = {0.f,0.f};
    v2f ne01 = {0.f,0.f}, no01 = {0.f,0.f}, ne23 = {0.f,0.f}, no23 = {0.f,0.f};

    const float4* __restrict__ M4 = (const float4*)&mom[0][0];  // 4 per seg

    #pragma unroll 4
    for (int s = 0; s < NSEG; s += 2) {
        {   // even segment s
            const float4 f0 = M4[s * 4 + 0];
            const float4 f1 = M4[s * 4 + 1];
            const float4 f2 = M4[s * 4 + 2];
            const float4 f3 = M4[s * 4 + 3];
            const v2f hd01 = horner6(u01, f0, f1);
            const v2f hn01 = horner6(u01, f2, f3);
            const v2f hd23 = horner6(u23, f0, f1);
            const v2f hn23 = horner6(u23, f2, f3);
            de01 = __builtin_elementwise_fma(Ee01, hd01, de01);
            ne01 = __builtin_elementwise_fma(Ee01, hn01, ne01);
            de23 = __builtin_elementwise_fma(Ee23, hd23, de23);
            ne23 = __builtin_elementwise_fma(Ee23, hn23, ne23);
            Ee01 = Ee01 * G2_01;
            Ee23 = Ee23 * G2_23;
        }
        {   // odd segment s+1
            const float4 f0 = M4[(s + 1) * 4 + 0];
            const float4 f1 = M4[(s + 1) * 4 + 1];
            const float4 f2 = M4[(s + 1) * 4 + 2];
            const float4 f3 = M4[(s + 1) * 4 + 3];
            const v2f hd01 = horner6(u01, f0, f1);
            const v2f hn01 = horner6(u01, f2, f3);
            const v2f hd23 = horner6(u23, f0, f1);
            const v2f hn23 = horner6(u23, f2, f3);
            do01 = __builtin_elementwise_fma(Eo01, hd01, do01);
            no01 = __builtin_elementwise_fma(Eo01, hn01, no01);
            do23 = __builtin_elementwise_fma(Eo23, hd23, do23);
            no23 = __builtin_elementwise_fma(Eo23, hn23, no23);
            Eo01 = Eo01 * G2_01;
            Eo23 = Eo23 * G2_23;
        }
    }

    const v2f den01 = de01 + do01, den23 = de23 + do23;
    const v2f num01 = ne01 + no01, num23 = ne23 + no23;

    const float wo = opw[0], bo = opb[0];
    const int rbase = blk * BSZ;
    out[(size_t)(rbase +   0 + lane) * NN + n] = fmaf(num01.x / den01.x, wo, bo);
    out[(size_t)(rbase +  64 + lane) * NN + n] = fmaf(num01.y / den01.y, wo, bo);
    out[(size_t)(rbase + 128 + lane) * NN + n] = fmaf(num23.x / den23.x, wo, bo);
    out[(size_t)(rbase + 192 + lane) * NN + n] = fmaf(num23.y / den23.y, wo, bo);
}

extern "C" void kernel_launch(void* const* d_in, const int* in_sizes, int n_in,
                              void* d_out, int out_size, void* d_ws, size_t ws_size,
                              hipStream_t stream) {
    const float* q   = (const float*)d_in[0];
    const float* k   = (const float*)d_in[1];
    const float* v   = (const float*)d_in[2];
    const float* ipw = (const float*)d_in[3];
    const float* ipb = (const float*)d_in[4];
    const float* opw = (const float*)d_in[5];
    const float* opb = (const float*)d_in[6];
    float* out = (float*)d_out;

    dim3 grid(NBLK * NN);   // 4096 WGs: one problem per single-wave WG
    dim3 block(64);
    BlockCrossAttn_kernel<<<grid, block, 0, stream>>>(q, k, v, ipw, ipb, opw, opb, out);
}

// Round 19
// 31.244 us; speedup vs baseline: 1.3552x; 1.0815x over previous
//
#include <hip/hip_runtime.h>

// L=32768, N=32, E=H=1, BS=256 -> 4096 rank-1 softmax problems:
//   out_i = sum_j 2^(a'_i k_j) v_j / sum_j 2^(a'_i k_j),  a' = (wq q + bq) log2e.
// No max-subtraction (f32-safe, scale-invariant; validated R5-R18).
//
// R19 = R18's segmented-Taylor attn (33.8us, verified) with the scattered
// gather replaced by coalesced loads from the verified R3 prepass planes.
// Theory: the 42->33.6 plateau's residue is memory TRANSACTION count -- the
// scattered gather is 12 wave-loads x 64 distinct 128B lines = 768
// transactions/wave (~12k/CU); coalesced planes cut that 16x. Attn structure,
// sort, moments, Horner row loop are bit-for-bit R18.

#define LL    32768
#define NN    32
#define BSZ   256
#define NBLK  (LL / BSZ)
#define NSEG  32
#define LOG2E 1.4426950408889634f
#define LN2   0.6931471805599453f

typedef float v2f __attribute__((ext_vector_type(2)));

// ---------------- Kernel P: projection + transpose (verified R3) ----------
__global__ __launch_bounds__(256) void proj_transpose_kernel(
    const float* __restrict__ q_in, const float* __restrict__ k_in,
    const float* __restrict__ v_in,
    const float* __restrict__ ipw,  const float* __restrict__ ipb,
    float* __restrict__ ws)
{
    __shared__ float sa[32][33], sk[32][33], sv[32][33];
    const int t  = threadIdx.x;
    const int r0 = blockIdx.x * 32;

    const float wq = ipw[0], wk = ipw[1], wv = ipw[2];
    const float bq = ipb[0], bk = ipb[1], bv = ipb[2];

    const int f = r0 * NN + t * 4;     // coalesced: 4 consecutive n of one row
    const float4 q4 = *reinterpret_cast<const float4*>(q_in + f);
    const float4 k4 = *reinterpret_cast<const float4*>(k_in + f);
    const float4 v4 = *reinterpret_cast<const float4*>(v_in + f);

    const int row = t >> 3, nc = (t & 7) * 4;
    sa[row][nc + 0] = fmaf(q4.x, wq, bq) * LOG2E;
    sa[row][nc + 1] = fmaf(q4.y, wq, bq) * LOG2E;
    sa[row][nc + 2] = fmaf(q4.z, wq, bq) * LOG2E;
    sa[row][nc + 3] = fmaf(q4.w, wq, bq) * LOG2E;
    sk[row][nc + 0] = fmaf(k4.x, wk, bk);
    sk[row][nc + 1] = fmaf(k4.y, wk, bk);
    sk[row][nc + 2] = fmaf(k4.z, wk, bk);
    sk[row][nc + 3] = fmaf(k4.w, wk, bk);
    sv[row][nc + 0] = fmaf(v4.x, wv, bv);
    sv[row][nc + 1] = fmaf(v4.y, wv, bv);
    sv[row][nc + 2] = fmaf(v4.z, wv, bv);
    sv[row][nc + 3] = fmaf(v4.w, wv, bv);
    __syncthreads();

    float* __restrict__ A = ws;
    float* __restrict__ K = ws + (size_t)LL * NN;
    float* __restrict__ V = ws + (size_t)2 * LL * NN;
    const int n = t >> 3, j0 = (t & 7) * 4;  // coalesced: 4 consecutive rows

    float4 o;
    o.x = sa[j0 + 0][n]; o.y = sa[j0 + 1][n]; o.z = sa[j0 + 2][n]; o.w = sa[j0 + 3][n];
    *reinterpret_cast<float4*>(A + (size_t)n * LL + r0 + j0) = o;
    o.x = sk[j0 + 0][n]; o.y = sk[j0 + 1][n]; o.z = sk[j0 + 2][n]; o.w = sk[j0 + 3][n];
    *reinterpret_cast<float4*>(K + (size_t)n * LL + r0 + j0) = o;
    o.x = sv[j0 + 0][n]; o.y = sv[j0 + 1][n]; o.z = sv[j0 + 2][n]; o.w = sv[j0 + 3][n];
    *reinterpret_cast<float4*>(V + (size_t)n * LL + r0 + j0) = o;
}

__device__ __forceinline__ v2f horner6(v2f u, float4 f0, float4 f1) {
    v2f h = {f1.z, f1.z};
    h = __builtin_elementwise_fma(h, u, (v2f){f1.y, f1.y});
    h = __builtin_elementwise_fma(h, u, (v2f){f1.x, f1.x});
    h = __builtin_elementwise_fma(h, u, (v2f){f0.w, f0.w});
    h = __builtin_elementwise_fma(h, u, (v2f){f0.z, f0.z});
    h = __builtin_elementwise_fma(h, u, (v2f){f0.y, f0.y});
    h = __builtin_elementwise_fma(h, u, (v2f){f0.x, f0.x});
    return h;
}

// ---------------- Kernel A: segmented-Taylor, coalesced gather ----------
__global__ __launch_bounds__(64) void attn_kernel(
    const float* __restrict__ ws,
    const float* __restrict__ opw, const float* __restrict__ opb,
    float* __restrict__ out)
{
    const int lane = threadIdx.x;        // 0..63, one wave per WG
    const int prob = blockIdx.x;         // 0..4095
    const int blk  = prob >> 5;
    const int n    = prob & 31;

    const float* __restrict__ A = ws;
    const float* __restrict__ K = ws + (size_t)LL * NN;
    const float* __restrict__ V = ws + (size_t)2 * LL * NN;
    const int base = n * LL + blk * BSZ;

    __shared__ alignas(16) float2 skv[BSZ];       // sorted (k, v)
    __shared__ alignas(16) float  mom[NSEG][16];  // D0..D6,_,N0..N6,_  (/d!)
    __shared__ int hist[128];

    // ---- coalesced gather: lane owns rows 4*lane + {0,1,2,3} ----
    const float4 af = *reinterpret_cast<const float4*>(A + base + 4 * lane);
    const float4 kf = *reinterpret_cast<const float4*>(K + base + 4 * lane);
    const float4 vf = *reinterpret_cast<const float4*>(V + base + 4 * lane);
    float a[4]  = {af.x, af.y, af.z, af.w};   // already * LOG2E
    float kr[4] = {kf.x, kf.y, kf.z, kf.w};
    float vr[4] = {vf.x, vf.y, vf.z, vf.w};

    // wave kmin/kmax
    float kmn = fminf(fminf(kr[0], kr[1]), fminf(kr[2], kr[3]));
    float kmx = fmaxf(fmaxf(kr[0], kr[1]), fmaxf(kr[2], kr[3]));
    #pragma unroll
    for (int off = 32; off >= 1; off >>= 1) {
        kmn = fminf(kmn, __shfl_xor(kmn, off));
        kmx = fmaxf(kmx, __shfl_xor(kmx, off));
    }
    const float rng  = kmx - kmn;
    const float binv = (rng > 0.f) ? (127.99f / rng) : 0.f;
    const float segw = rng * (1.0f / NSEG);

    // ---- counting sort by 7-bit quantized k (verified R13-R18) ----
    hist[lane]      = 0;
    hist[lane + 64] = 0;
    __syncthreads();

    int bin[4];
    #pragma unroll
    for (int r = 0; r < 4; ++r) {
        int b = (int)((kr[r] - kmn) * binv);
        bin[r] = (b < 0) ? 0 : ((b > 127) ? 127 : b);
        atomicAdd(&hist[bin[r]], 1);      // wave-private, lane-ordered
    }
    __syncthreads();

    {
        const int c0 = hist[lane];
        const int c1 = hist[lane + 64];
        int i0 = c0, i1 = c1;
        #pragma unroll
        for (int off = 1; off <= 32; off <<= 1) {
            const int t0 = __shfl_up(i0, off);
            const int t1 = __shfl_up(i1, off);
            if (lane >= off) { i0 += t0; i1 += t1; }
        }
        const int tot0 = __shfl(i0, 63);
        hist[lane]      = i0 - c0;        // exclusive starts
        hist[lane + 64] = i1 - c1 + tot0;
    }
    __syncthreads();

    #pragma unroll
    for (int r = 0; r < 4; ++r) {
        const int slot = atomicAdd(&hist[bin[r]], 1);
        skv[slot] = make_float2(kr[r], vr[r]);
    }
    __syncthreads();
    // hist[b] = END offset of bin b

    // ---- moments: 2 lanes per segment, contiguous half-ranges (R18) ----
    {
        const int s    = lane >> 1;
        const int half = lane & 1;
        const int beg0 = (s == 0) ? 0 : hist[4 * s - 1];
        const int end0 = hist[4 * s + 3];
        const int mid  = beg0 + ((end0 - beg0 + 1) >> 1);
        const int beg  = half ? mid  : beg0;
        const int end  = half ? end0 : mid;
        const float cs = kmn + (s + 0.5f) * segw;

        float m0=0.f,m1=0.f,m2=0.f,m3=0.f,m4=0.f,m5=0.f,m6=0.f;
        float n0=0.f,n1=0.f,n2=0.f,n3=0.f,n4=0.f,n5=0.f,n6=0.f;
        for (int e = beg; e < end; ++e) {
            const float2 kv = skv[e];
            const float dk = kv.x - cs;
            const float vv = kv.y;
            const float p1 = dk, p2 = p1 * dk, p3 = p2 * dk;
            const float p4 = p3 * dk, p5 = p4 * dk, p6 = p5 * dk;
            m0 += 1.f; m1 += p1; m2 += p2; m3 += p3; m4 += p4; m5 += p5; m6 += p6;
            n0 += vv;
            n1 = fmaf(vv, p1, n1); n2 = fmaf(vv, p2, n2); n3 = fmaf(vv, p3, n3);
            n4 = fmaf(vv, p4, n4); n5 = fmaf(vv, p5, n5); n6 = fmaf(vv, p6, n6);
        }
        m0 += __shfl_xor(m0, 1); m1 += __shfl_xor(m1, 1); m2 += __shfl_xor(m2, 1);
        m3 += __shfl_xor(m3, 1); m4 += __shfl_xor(m4, 1); m5 += __shfl_xor(m5, 1);
        m6 += __shfl_xor(m6, 1);
        n0 += __shfl_xor(n0, 1); n1 += __shfl_xor(n1, 1); n2 += __shfl_xor(n2, 1);
        n3 += __shfl_xor(n3, 1); n4 += __shfl_xor(n4, 1); n5 += __shfl_xor(n5, 1);
        n6 += __shfl_xor(n6, 1);

        float4* mp = (float4*)&mom[s][0];
        if (!half) {
            mp[0] = make_float4(m0, m1, m2 * 0.5f, m3 * (1.f / 6.f));
            mp[1] = make_float4(m4 * (1.f / 24.f), m5 * (1.f / 120.f),
                                m6 * (1.f / 720.f), 0.f);
        } else {
            mp[2] = make_float4(n0, n1, n2 * 0.5f, n3 * (1.f / 6.f));
            mp[3] = make_float4(n4 * (1.f / 24.f), n5 * (1.f / 120.f),
                                n6 * (1.f / 720.f), 0.f);
        }
    }
    __syncthreads();

    // ---- row loop: 4 rows/thread, E-recurrence (2 chains), deg-6 Horner ----
    const v2f u01 = {a[0] * LN2, a[1] * LN2};
    const v2f u23 = {a[2] * LN2, a[3] * LN2};
    const float c0s = kmn + 0.5f * segw;

    v2f Ee01, Ee23, g01, g23;
    Ee01.x = __builtin_amdgcn_exp2f(a[0] * c0s);
    Ee01.y = __builtin_amdgcn_exp2f(a[1] * c0s);
    Ee23.x = __builtin_amdgcn_exp2f(a[2] * c0s);
    Ee23.y = __builtin_amdgcn_exp2f(a[3] * c0s);
    g01.x  = __builtin_amdgcn_exp2f(a[0] * segw);
    g01.y  = __builtin_amdgcn_exp2f(a[1] * segw);
    g23.x  = __builtin_amdgcn_exp2f(a[2] * segw);
    g23.y  = __builtin_amdgcn_exp2f(a[3] * segw);
    const v2f G2_01 = g01 * g01;
    const v2f G2_23 = g23 * g23;
    v2f Eo01 = Ee01 * g01;
    v2f Eo23 = Ee23 * g23;

    v2f de01 = {0.f,0.f}, do01 = {0.f,0.f}, de23 = {0.f,0.f}, do23 = {0.f,0.f};
    v2f ne01 = {0.f,0.f}, no01 = {0.f,0.f}, ne23 = {0.f,0.f}, no23 = {0.f,0.f};

    const float4* __restrict__ M4 = (const float4*)&mom[0][0];

    #pragma unroll 4
    for (int s = 0; s < NSEG; s += 2) {
        {
            const float4 f0 = M4[s * 4 + 0];
            const float4 f1 = M4[s * 4 + 1];
            const float4 f2 = M4[s * 4 + 2];
            const float4 f3 = M4[s * 4 + 3];
            const v2f hd01 = horner6(u01, f0, f1);
            const v2f hn01 = horner6(u01, f2, f3);
            const v2f hd23 = horner6(u23, f0, f1);
            const v2f hn23 = horner6(u23, f2, f3);
            de01 = __builtin_elementwise_fma(Ee01, hd01, de01);
            ne01 = __builtin_elementwise_fma(Ee01, hn01, ne01);
            de23 = __builtin_elementwise_fma(Ee23, hd23, de23);
            ne23 = __builtin_elementwise_fma(Ee23, hn23, ne23);
            Ee01 = Ee01 * G2_01;
            Ee23 = Ee23 * G2_23;
        }
        {
            const float4 f0 = M4[(s + 1) * 4 + 0];
            const float4 f1 = M4[(s + 1) * 4 + 1];
            const float4 f2 = M4[(s + 1) * 4 + 2];
            const float4 f3 = M4[(s + 1) * 4 + 3];
            const v2f hd01 = horner6(u01, f0, f1);
            const v2f hn01 = horner6(u01, f2, f3);
            const v2f hd23 = horner6(u23, f0, f1);
            const v2f hn23 = horner6(u23, f2, f3);
            do01 = __builtin_elementwise_fma(Eo01, hd01, do01);
            no01 = __builtin_elementwise_fma(Eo01, hn01, no01);
            do23 = __builtin_elementwise_fma(Eo23, hd23, do23);
            no23 = __builtin_elementwise_fma(Eo23, hn23, no23);
            Eo01 = Eo01 * G2_01;
            Eo23 = Eo23 * G2_23;
        }
    }

    const v2f den01 = de01 + do01, den23 = de23 + do23;
    const v2f num01 = ne01 + no01, num23 = ne23 + no23;

    const float wo = opw[0], bo = opb[0];
    const int rbase = blk * BSZ + 4 * lane;
    out[(size_t)(rbase + 0) * NN + n] = fmaf(num01.x / den01.x, wo, bo);
    out[(size_t)(rbase + 1) * NN + n] = fmaf(num01.y / den01.y, wo, bo);
    out[(size_t)(rbase + 2) * NN + n] = fmaf(num23.x / den23.x, wo, bo);
    out[(size_t)(rbase + 3) * NN + n] = fmaf(num23.y / den23.y, wo, bo);
}

extern "C" void kernel_launch(void* const* d_in, const int* in_sizes, int n_in,
                              void* d_out, int out_size, void* d_ws, size_t ws_size,
                              hipStream_t stream) {
    const float* q   = (const float*)d_in[0];
    const float* k   = (const float*)d_in[1];
    const float* v   = (const float*)d_in[2];
    const float* ipw = (const float*)d_in[3];
    const float* ipb = (const float*)d_in[4];
    const float* opw = (const float*)d_in[5];
    const float* opb = (const float*)d_in[6];
    float* out = (float*)d_out;
    float* ws  = (float*)d_ws;   // needs 3*L*N*4 = 12.6 MB

    proj_transpose_kernel<<<dim3(LL / 32), dim3(256), 0, stream>>>(q, k, v, ipw, ipb, ws);
    attn_kernel<<<dim3(NBLK * NN), dim3(64), 0, stream>>>(ws, opw, opb, out);
}